// Round 1
// 62.719 us; speedup vs baseline: 1.0095x; 1.0095x over previous
//
#include <hip/hip_runtime.h>

// desc[b,f,i,:] = sum_j s(|ri-rj|) * (ri-rj), s = smooth cosine cutoff
// V2: 512 blocks = 16 frames x 32-i blocks, 256 threads = 16 i-groups x 16 j-chunks.
//  - 2 i-atoms per thread: one ds_read_b128 feeds 2 pairs (halves LDS traffic).
//  - Staging: 3 coalesced float4 loads/thread (vs 12 scalar) -> 4 atoms/thread.
//  - LDS padded to 65 float4 per 64-atom group (phys = a + (a>>6)): j-loop is
//    base + immediate-offset ds_read_b128, zero per-iter address VALU; the 4
//    distinct chunk bases in a wave are 16B apart mod 128 -> conflict-free
//    broadcast (16 lanes/address).

#define NA   1024
#define IPB  32     // i atoms per block
#define NJC  16     // j-chunks
#define JLEN 64     // j per chunk

__global__ __launch_bounds__(256) void desc_kernel(const float* __restrict__ coord,
                                                   float* __restrict__ out) {
    __shared__ float4 s_c[NA + NA / 64];   // padded coords: phys = a + (a>>6)
    __shared__ float  s_red[4][16][2][3];  // per-wave partials

    const int tid   = threadIdx.x;
    const int blk   = blockIdx.x;
    const int frame = blk >> 5;   // 32 i-blocks per frame
    const int ibk   = blk & 31;
    const int ig    = tid & 15;   // i-group (2 atoms each)
    const int jc    = tid >> 4;   // 16 chunks of 64 j

    // ---- stage frame coords: 4 atoms per thread via 3 coalesced float4 loads
    const float4* gf4 = (const float4*)(coord + frame * (NA * 3));
    {
        const float4 f0 = gf4[3 * tid + 0];
        const float4 f1 = gf4[3 * tid + 1];
        const float4 f2 = gf4[3 * tid + 2];
        const int a0 = 4 * tid;
        const int p  = a0 + (a0 >> 6);     // 4 atoms never straddle a 64-group
        s_c[p + 0] = make_float4(f0.x, f0.y, f0.z, 0.0f);
        s_c[p + 1] = make_float4(f0.w, f1.x, f1.y, 0.0f);
        s_c[p + 2] = make_float4(f1.z, f1.w, f2.x, 0.0f);
        s_c[p + 3] = make_float4(f2.y, f2.z, f2.w, 0.0f);
    }
    __syncthreads();

    const int    ia  = ibk * IPB + 2 * ig;
    const int    ip  = ia + (ia >> 6);     // ia even -> ia, ia+1 in same group
    const float4 ci0 = s_c[ip];
    const float4 ci1 = s_c[ip + 1];

    const float4* pj = &s_c[65 * jc];      // chunk base: 64*jc + pad(jc)

    float ax0 = 0.f, ay0 = 0.f, az0 = 0.f;
    float ax1 = 0.f, ay1 = 0.f, az1 = 0.f;
    const float INV11 = 1.0f / 11.0f;      // rev = (r - 0.5)/(2*5.5) revolutions
    const float OFF   = -0.5f / 11.0f;

#pragma unroll 8
    for (int t = 0; t < JLEN; ++t) {
        const float4 cj = pj[t];           // ds_read_b128, immediate offset
        {
            const float dx = ci0.x - cj.x, dy = ci0.y - cj.y, dz = ci0.z - cj.z;
            const float d2 = fmaf(dx, dx, fmaf(dy, dy, fmaf(dz, dz, 1e-10f)));
            const float r  = __builtin_amdgcn_sqrtf(d2);
            float rev = fmaf(r, INV11, OFF);
            rev = fminf(fmaxf(rev, 0.0f), 0.5f);   // v_med3 -> exact {1, cos, 0}
            const float s = fmaf(0.5f, __builtin_amdgcn_cosf(rev), 0.5f);
            ax0 = fmaf(s, dx, ax0); ay0 = fmaf(s, dy, ay0); az0 = fmaf(s, dz, az0);
        }
        {
            const float dx = ci1.x - cj.x, dy = ci1.y - cj.y, dz = ci1.z - cj.z;
            const float d2 = fmaf(dx, dx, fmaf(dy, dy, fmaf(dz, dz, 1e-10f)));
            const float r  = __builtin_amdgcn_sqrtf(d2);
            float rev = fmaf(r, INV11, OFF);
            rev = fminf(fmaxf(rev, 0.0f), 0.5f);
            const float s = fmaf(0.5f, __builtin_amdgcn_cosf(rev), 0.5f);
            ax1 = fmaf(s, dx, ax1); ay1 = fmaf(s, dy, ay1); az1 = fmaf(s, dz, az1);
        }
    }

    // reduce the 4 within-wave jc values (tid bits 4,5)
    ax0 += __shfl_xor(ax0, 16, 64); ax0 += __shfl_xor(ax0, 32, 64);
    ay0 += __shfl_xor(ay0, 16, 64); ay0 += __shfl_xor(ay0, 32, 64);
    az0 += __shfl_xor(az0, 16, 64); az0 += __shfl_xor(az0, 32, 64);
    ax1 += __shfl_xor(ax1, 16, 64); ax1 += __shfl_xor(ax1, 32, 64);
    ay1 += __shfl_xor(ay1, 16, 64); ay1 += __shfl_xor(ay1, 32, 64);
    az1 += __shfl_xor(az1, 16, 64); az1 += __shfl_xor(az1, 32, 64);

    const int wave = tid >> 6;
    if ((tid & 48) == 0) {
        s_red[wave][ig][0][0] = ax0; s_red[wave][ig][0][1] = ay0; s_red[wave][ig][0][2] = az0;
        s_red[wave][ig][1][0] = ax1; s_red[wave][ig][1][1] = ay1; s_red[wave][ig][1][2] = az1;
    }
    __syncthreads();

    // final reduce across 4 waves; 96 threads write 32 atoms x 3 comps contiguously
    if (tid < IPB * 3) {
        const int il   = tid / 3;
        const int comp = tid - il * 3;
        const int g    = il >> 1;
        const int ii   = il & 1;
        const float v = s_red[0][g][ii][comp] + s_red[1][g][ii][comp] +
                        s_red[2][g][ii][comp] + s_red[3][g][ii][comp];
        out[frame * (NA * 3) + (ibk * IPB + il) * 3 + comp] = v;
    }
}

extern "C" void kernel_launch(void* const* d_in, const int* in_sizes, int n_in,
                              void* d_out, int out_size, void* d_ws, size_t ws_size,
                              hipStream_t stream) {
    const float* coord = (const float*)d_in[0];
    float*       out   = (float*)d_out;
    (void)d_ws; (void)ws_size; (void)n_in; (void)out_size;

    const int frames = in_sizes[0] / (NA * 3);   // B*F = 16
    const int blocks = frames * (NA / IPB);      // 512

    hipLaunchKernelGGL(desc_kernel, dim3(blocks), dim3(256), 0, stream, coord, out);
}